// Round 3
// baseline (200.411 us; speedup 1.0000x reference)
//
#include <hip/hip_runtime.h>
#include <math.h>

#define EPS 1e-7f
#define NB_BCE 1024   // blocks doing the BCE base-sum role

// BCE-with-logits base term (target-independent part): max(l,0) + log1p(exp(-|l|))
__device__ __forceinline__ float bce_base(float l) {
    return fmaxf(l, 0.0f) + __logf(1.0f + __expf(-fabsf(l)));
}

__device__ __forceinline__ float sigmoidf_(float x) { return 1.0f / (1.0f + expf(-x)); }

// Single fused kernel.
//  blocks [0, NB_BCE)            : grid-stride BCE base sum over channel 0 of all
//                                  3 pyramid levels -> ws_c[bid]
//  blocks [NB_BCE, NB_BCE + 3B)  : per-(image,level) positive-cell work:
//                                  candidate scatter (<=96 cells), CIoU box loss,
//                                  obj_t BCE correction -> ws_box/ws_corr/ws_npos
//  last block to finish          : reduces all partials (fixed order) -> out[0]
__global__ __launch_bounds__(256) void det_main(
    const float* __restrict__ pred0,   // (B,5,52,52)
    const float* __restrict__ pred1,   // (B,5,26,26)
    const float* __restrict__ pred2,   // (B,5,13,13)
    const float* __restrict__ gt,      // (B,32,4)
    unsigned*    ws_counter,           // [1] zeroed by memset each call
    float*       ws_c,                 // [NB_BCE]
    float*       ws_box,               // [3B]  (already / max(npos,1))
    float*       ws_corr,              // [3B]  (sum of l0*obj_t)
    int*         ws_npos,              // [3B]
    int B,
    float* __restrict__ out)
{
    __shared__ int   s_map[52 * 52];
    __shared__ float s_gt[128];
    __shared__ int   s_cell[96];
    __shared__ float s_redf[12];
    __shared__ int   s_redi[8];
    __shared__ int   s_isLast;

    const int tid = threadIdx.x;
    const int bid = blockIdx.x;
    const int nPL = 3 * B;

    if (bid < NB_BCE) {
        // ---------------- BCE base role ----------------
        const unsigned E0 = (unsigned)B * 2704u;            // level-0 cells
        const unsigned E1 = (unsigned)B * 676u;
        const unsigned E2 = (unsigned)B * 169u;
        const unsigned NV4 = (E0 + E1) >> 2;                // float4 items (both %4==0)
        float acc = 0.0f;

        for (unsigned v = (unsigned)bid * 256u + tid; v < NV4; v += NB_BCE * 256u) {
            const unsigned idx = v << 2;
            const float* p;
            if (idx < E0) {
                const unsigned b = idx / 2704u;
                const unsigned i = idx - b * 2704u;
                p = pred0 + (size_t)b * 13520u + i;
            } else {
                const unsigned j = idx - E0;
                const unsigned b = j / 676u;
                const unsigned i = j - b * 676u;
                p = pred1 + (size_t)b * 3380u + i;
            }
            const float4 l = *reinterpret_cast<const float4*>(p);
            acc += bce_base(l.x) + bce_base(l.y) + bce_base(l.z) + bce_base(l.w);
        }
        // level 2 (169 not %4) scalar
        for (unsigned j = (unsigned)bid * 256u + tid; j < E2; j += NB_BCE * 256u) {
            const unsigned b = j / 169u;
            const unsigned i = j - b * 169u;
            acc += bce_base(pred2[(size_t)b * 845u + i]);
        }

        // block reduce -> ws_c[bid]
        for (int off = 32; off > 0; off >>= 1) acc += __shfl_down(acc, off);
        if ((tid & 63) == 0) s_redf[tid >> 6] = acc;
        __syncthreads();
        if (tid == 0) ws_c[bid] = s_redf[0] + s_redf[1] + s_redf[2] + s_redf[3];
    } else {
        // ---------------- positives role ----------------
        const int pbid  = bid - NB_BCE;       // 0 .. 3B-1
        const int level = pbid % 3;
        const int b     = pbid / 3;

        const float* pred;
        int Wd;
        if (level == 0)      { pred = pred0; Wd = 52; }
        else if (level == 1) { pred = pred1; Wd = 26; }
        else                 { pred = pred2; Wd = 13; }
        const int   HW = Wd * Wd;
        const float S  = (float)Wd;
        const float sc = 1.0f / S;

        if (tid < 128) s_gt[tid] = gt[(size_t)b * 128 + tid];
        __syncthreads();

        // candidate generation: 32 gts -> up to 96 (cell, gi); slot k has gi = k & 31
        if (tid < 32) {
            const int n = tid;
            const float gx = s_gt[n * 4 + 0] * S;
            const float gy = s_gt[n * 4 + 1] * S;
            int col = (int)gx; col = min(max(col, 0), Wd - 1);
            int row = (int)gy; row = min(max(row, 0), Wd - 1);
            const float off_x = gx - (float)col;
            const float off_y = gy - (float)row;
            s_cell[n] = row * Wd + col;
            int col_n, row_n; bool vx, vy;
            if (off_x < 0.5f) { col_n = col - 1; vx = (col > 0); }
            else              { col_n = col + 1; vx = (col < Wd - 1); }
            if (off_y < 0.5f) { row_n = row - 1; vy = (row > 0); }
            else              { row_n = row + 1; vy = (row < Wd - 1); }
            s_cell[32 + n] = vx ? (row * Wd + col_n) : -1;
            s_cell[64 + n] = vy ? (row_n * Wd + col) : -1;
        }
        __syncthreads();

        int c = -1;
        if (tid < 96) c = s_cell[tid];
        if (c >= 0) s_map[c] = -1;            // init only touched cells
        __syncthreads();
        if (c >= 0) atomicMax(&s_map[c], tid & 31);
        __syncthreads();

        // winner: unique slot per positive cell (max gi wins; ties impossible)
        const bool winner = (c >= 0) && (s_map[c] == (tid & 31));

        float box_v = 0.0f, corr_v = 0.0f;
        int np_v = 0;
        if (winner) {
            np_v = 1;
            const int gi = s_map[c];
            const float* base = pred + (size_t)b * 5 * HW;
            const float l0 = base[c];
            const float l1 = base[HW + c];
            const float l2 = base[2 * HW + c];
            const float l3 = base[3 * HW + c];
            const float l4 = base[4 * HW + c];
            const float ccol = (float)(c % Wd);
            const float crow = (float)(c / Wd);
            const float p_cx = (sigmoidf_(l1) * 2.0f - 0.5f + ccol) * sc;
            const float p_cy = (sigmoidf_(l2) * 2.0f - 0.5f + crow) * sc;
            const float p_w  = expf(fminf(fmaxf(l3, -5.0f), 5.0f)) * sc;
            const float p_h  = expf(fminf(fmaxf(l4, -5.0f), 5.0f)) * sc;
            const float t_cx = s_gt[gi * 4 + 0];
            const float t_cy = s_gt[gi * 4 + 1];
            const float t_w  = s_gt[gi * 4 + 2];
            const float t_h  = s_gt[gi * 4 + 3];

            const float b1x1 = p_cx - p_w * 0.5f, b1y1 = p_cy - p_h * 0.5f;
            const float b1x2 = p_cx + p_w * 0.5f, b1y2 = p_cy + p_h * 0.5f;
            const float b2x1 = t_cx - t_w * 0.5f, b2y1 = t_cy - t_h * 0.5f;
            const float b2x2 = t_cx + t_w * 0.5f, b2y2 = t_cy + t_h * 0.5f;

            const float w1 = b1x2 - b1x1, h1 = b1y2 - b1y1;
            const float w2 = b2x2 - b2x1, h2 = b2y2 - b2y1;

            const float iw = fmaxf(fminf(b1x2, b2x2) - fmaxf(b1x1, b2x1), 0.0f);
            const float ih = fmaxf(fminf(b1y2, b2y2) - fmaxf(b1y1, b2y1), 0.0f);
            const float inter = iw * ih;
            const float uni = w1 * h1 + w2 * h2 - inter + EPS;
            const float iou = inter / uni;

            const float cw = fmaxf(b1x2, b2x2) - fminf(b1x1, b2x1);
            const float ch = fmaxf(b1y2, b2y2) - fminf(b1y1, b2y1);
            const float c2 = cw * cw + ch * ch + EPS;
            const float dx = b2x1 + b2x2 - b1x1 - b1x2;
            const float dy = b2y1 + b2y2 - b1y1 - b1y2;
            const float rho2 = (dx * dx + dy * dy) * 0.25f;
            const float datan = atanf(w2 / (h2 + EPS)) - atanf(w1 / (h1 + EPS));
            const float v = (4.0f / (float)(M_PI * M_PI)) * datan * datan;
            const float alpha = v / (v - iou + 1.0f + EPS);
            const float ciou = 1.0f - iou + rho2 / c2 + alpha * v;
            box_v = fmaxf(ciou, 0.0f);

            const float area_p = fmaxf(p_w * p_h, EPS);
            const float area_t = fmaxf(t_w * t_h, EPS);
            float iou2 = inter / (area_p + area_t - inter + EPS);
            iou2 = fminf(fmaxf(iou2, 0.0f), 1.0f);
            corr_v = l0 * iou2;               // BCE correction term: -sum(l0*obj_t)
        }

        for (int off = 32; off > 0; off >>= 1) {
            box_v  += __shfl_down(box_v, off);
            corr_v += __shfl_down(corr_v, off);
            np_v   += __shfl_down(np_v, off);
        }
        const int wave = tid >> 6;
        if ((tid & 63) == 0) {
            s_redf[wave * 2 + 0] = box_v;
            s_redf[wave * 2 + 1] = corr_v;
            s_redi[wave] = np_v;
        }
        __syncthreads();
        if (tid == 0) {
            float box_t = 0.0f, corr_t = 0.0f; int np_t = 0;
            for (int w = 0; w < 4; w++) {
                box_t  += s_redf[w * 2 + 0];
                corr_t += s_redf[w * 2 + 1];
                np_t   += s_redi[w];
            }
            ws_box[pbid]  = box_t / (float)max(np_t, 1);
            ws_corr[pbid] = corr_t;
            ws_npos[pbid] = np_t;
        }
    }

    // ---------------- last-block finalize ----------------
    __threadfence();                          // release partials (device scope)
    if (tid == 0) {
        const unsigned t = atomicAdd(ws_counter, 1u);
        s_isLast = (t == (unsigned)(gridDim.x - 1)) ? 1 : 0;
    }
    __syncthreads();
    if (!s_isLast) return;
    __threadfence();                          // acquire partials

    volatile const float* v_c    = ws_c;
    volatile const float* v_box  = ws_box;
    volatile const float* v_corr = ws_corr;
    volatile const int*   v_npos = ws_npos;

    float box = 0.0f, corr = 0.0f, bce = 0.0f;
    int pos = 0, items = 0;
    for (int i = tid; i < nPL; i += 256) {
        box  += v_box[i];
        corr += v_corr[i];
        const int np = v_npos[i];
        pos += np;
        items += (np > 0) ? 1 : 0;
    }
    for (int i = tid; i < NB_BCE; i += 256) bce += v_c[i];

    for (int off = 32; off > 0; off >>= 1) {
        box   += __shfl_down(box, off);
        corr  += __shfl_down(corr, off);
        bce   += __shfl_down(bce, off);
        pos   += __shfl_down(pos, off);
        items += __shfl_down(items, off);
    }
    const int wave = tid >> 6;
    if ((tid & 63) == 0) {
        s_redf[wave * 3 + 0] = box;
        s_redf[wave * 3 + 1] = corr;
        s_redf[wave * 3 + 2] = bce;
        s_redi[wave * 2 + 0] = pos;
        s_redi[wave * 2 + 1] = items;
    }
    __syncthreads();
    if (tid == 0) {
        float box_t = 0.0f, corr_t = 0.0f, bce_t = 0.0f;
        int pos_t = 0, it_t = 0;
        for (int w = 0; w < 4; w++) {
            box_t  += s_redf[w * 3 + 0];
            corr_t += s_redf[w * 3 + 1];
            bce_t  += s_redf[w * 3 + 2];
            pos_t  += s_redi[w * 2 + 0];
            it_t   += s_redi[w * 2 + 1];
        }
        const float total_obj = (bce_t - corr_t) / fmaxf((float)pos_t, 1.0f);
        const float total_box = box_t / (float)max(it_t, 1);
        out[0] = total_obj + 5.0f * total_box;
    }
}

extern "C" void kernel_launch(void* const* d_in, const int* in_sizes, int n_in,
                              void* d_out, int out_size, void* d_ws, size_t ws_size,
                              hipStream_t stream)
{
    const float* pred0 = (const float*)d_in[0];
    const float* pred1 = (const float*)d_in[1];
    const float* pred2 = (const float*)d_in[2];
    const float* gt    = (const float*)d_in[3];
    float* out = (float*)d_out;

    const int B   = in_sizes[3] / (32 * 4);   // 512
    const int nPL = 3 * B;                    // 1536

    // ws layout: counter(4B pad to 16) | ws_c[NB_BCE] | ws_box[nPL] | ws_corr[nPL] | ws_npos[nPL]
    unsigned* ws_counter = (unsigned*)d_ws;
    float* ws_c    = (float*)((char*)d_ws + 16);
    float* ws_box  = ws_c + NB_BCE;
    float* ws_corr = ws_box + nPL;
    int*   ws_npos = (int*)(ws_corr + nPL);

    hipMemsetAsync(ws_counter, 0, 4, stream);
    det_main<<<dim3(NB_BCE + nPL), dim3(256), 0, stream>>>(
        pred0, pred1, pred2, gt, ws_counter, ws_c, ws_box, ws_corr, ws_npos, B, out);
}

// Round 4
// 129.519 us; speedup vs baseline: 1.5474x; 1.5474x over previous
//
#include <hip/hip_runtime.h>
#include <math.h>

#define EPS 1e-7f
#define NB_BCE 1024   // blocks doing the BCE base-sum role

// BCE-with-logits base term (target-independent part): max(l,0) + log1p(exp(-|l|))
__device__ __forceinline__ float bce_base(float l) {
    return fmaxf(l, 0.0f) + __logf(1.0f + __expf(-fabsf(l)));
}

__device__ __forceinline__ float sigmoidf_(float x) { return 1.0f / (1.0f + expf(-x)); }

// Single fused kernel, no fences. Cross-block communication is exclusively via
// device-scope global atomics (coherent point), which round 1 validated on this
// chip. Accumulators: f[0] = bce_sum - corr_sum, f[1] = sum(box_i / npos_i),
// i[0] = total_pos, i[1] = n_items. Last block (ticket) computes out[0].
__global__ __launch_bounds__(256) void det_main(
    const float* __restrict__ pred0,   // (B,5,52,52)
    const float* __restrict__ pred1,   // (B,5,26,26)
    const float* __restrict__ pred2,   // (B,5,13,13)
    const float* __restrict__ gt,      // (B,32,4)
    unsigned*    ws_counter,           // [1]  zeroed each call
    float*       ws_f,                 // [2]  zeroed each call
    int*         ws_i,                 // [2]  zeroed each call
    int B,
    float* __restrict__ out)
{
    __shared__ int   s_map[52 * 52];
    __shared__ float s_gt[128];
    __shared__ int   s_cell[96];
    __shared__ float s_redf[8];
    __shared__ int   s_redi[4];

    const int tid = threadIdx.x;
    const int bid = blockIdx.x;

    if (bid < NB_BCE) {
        // ---------------- BCE base role ----------------
        const unsigned E0 = (unsigned)B * 2704u;            // level-0 cells
        const unsigned E1 = (unsigned)B * 676u;
        const unsigned E2 = (unsigned)B * 169u;
        const unsigned NV4 = (E0 + E1) >> 2;                // float4 items (both %4==0)
        float acc = 0.0f;

        for (unsigned v = (unsigned)bid * 256u + tid; v < NV4; v += NB_BCE * 256u) {
            const unsigned idx = v << 2;
            const float* p;
            if (idx < E0) {
                const unsigned b = idx / 2704u;
                const unsigned i = idx - b * 2704u;
                p = pred0 + (size_t)b * 13520u + i;
            } else {
                const unsigned j = idx - E0;
                const unsigned b = j / 676u;
                const unsigned i = j - b * 676u;
                p = pred1 + (size_t)b * 3380u + i;
            }
            const float4 l = *reinterpret_cast<const float4*>(p);
            acc += bce_base(l.x) + bce_base(l.y) + bce_base(l.z) + bce_base(l.w);
        }
        // level 2 (169 not %4) scalar
        for (unsigned j = (unsigned)bid * 256u + tid; j < E2; j += NB_BCE * 256u) {
            const unsigned b = j / 169u;
            const unsigned i = j - b * 169u;
            acc += bce_base(pred2[(size_t)b * 845u + i]);
        }

        for (int off = 32; off > 0; off >>= 1) acc += __shfl_down(acc, off);
        if ((tid & 63) == 0) s_redf[tid >> 6] = acc;
        __syncthreads();
        if (tid == 0) {
            const float bce_t = s_redf[0] + s_redf[1] + s_redf[2] + s_redf[3];
            atomicAdd(&ws_f[0], bce_t);
        }
    } else {
        // ---------------- positives role ----------------
        const int pbid  = bid - NB_BCE;       // 0 .. 3B-1
        const int level = pbid % 3;
        const int b     = pbid / 3;

        const float* pred;
        int Wd;
        if (level == 0)      { pred = pred0; Wd = 52; }
        else if (level == 1) { pred = pred1; Wd = 26; }
        else                 { pred = pred2; Wd = 13; }
        const int   HW = Wd * Wd;
        const float S  = (float)Wd;
        const float sc = 1.0f / S;

        if (tid < 128) s_gt[tid] = gt[(size_t)b * 128 + tid];
        __syncthreads();

        // candidate generation: 32 gts -> up to 96 (cell, gi); slot k has gi = k & 31
        if (tid < 32) {
            const int n = tid;
            const float gx = s_gt[n * 4 + 0] * S;
            const float gy = s_gt[n * 4 + 1] * S;
            int col = (int)gx; col = min(max(col, 0), Wd - 1);
            int row = (int)gy; row = min(max(row, 0), Wd - 1);
            const float off_x = gx - (float)col;
            const float off_y = gy - (float)row;
            s_cell[n] = row * Wd + col;
            int col_n, row_n; bool vx, vy;
            if (off_x < 0.5f) { col_n = col - 1; vx = (col > 0); }
            else              { col_n = col + 1; vx = (col < Wd - 1); }
            if (off_y < 0.5f) { row_n = row - 1; vy = (row > 0); }
            else              { row_n = row + 1; vy = (row < Wd - 1); }
            s_cell[32 + n] = vx ? (row * Wd + col_n) : -1;
            s_cell[64 + n] = vy ? (row_n * Wd + col) : -1;
        }
        __syncthreads();

        int c = -1;
        if (tid < 96) c = s_cell[tid];
        if (c >= 0) s_map[c] = -1;            // init only touched cells
        __syncthreads();
        if (c >= 0) atomicMax(&s_map[c], tid & 31);
        __syncthreads();

        // winner: unique slot per positive cell (max gi wins; ties impossible)
        const bool winner = (c >= 0) && (s_map[c] == (tid & 31));

        float box_v = 0.0f, corr_v = 0.0f;
        int np_v = 0;
        if (winner) {
            np_v = 1;
            const int gi = s_map[c];
            const float* base = pred + (size_t)b * 5 * HW;
            const float l0 = base[c];
            const float l1 = base[HW + c];
            const float l2 = base[2 * HW + c];
            const float l3 = base[3 * HW + c];
            const float l4 = base[4 * HW + c];
            const float ccol = (float)(c % Wd);
            const float crow = (float)(c / Wd);
            const float p_cx = (sigmoidf_(l1) * 2.0f - 0.5f + ccol) * sc;
            const float p_cy = (sigmoidf_(l2) * 2.0f - 0.5f + crow) * sc;
            const float p_w  = expf(fminf(fmaxf(l3, -5.0f), 5.0f)) * sc;
            const float p_h  = expf(fminf(fmaxf(l4, -5.0f), 5.0f)) * sc;
            const float t_cx = s_gt[gi * 4 + 0];
            const float t_cy = s_gt[gi * 4 + 1];
            const float t_w  = s_gt[gi * 4 + 2];
            const float t_h  = s_gt[gi * 4 + 3];

            const float b1x1 = p_cx - p_w * 0.5f, b1y1 = p_cy - p_h * 0.5f;
            const float b1x2 = p_cx + p_w * 0.5f, b1y2 = p_cy + p_h * 0.5f;
            const float b2x1 = t_cx - t_w * 0.5f, b2y1 = t_cy - t_h * 0.5f;
            const float b2x2 = t_cx + t_w * 0.5f, b2y2 = t_cy + t_h * 0.5f;

            const float w1 = b1x2 - b1x1, h1 = b1y2 - b1y1;
            const float w2 = b2x2 - b2x1, h2 = b2y2 - b2y1;

            const float iw = fmaxf(fminf(b1x2, b2x2) - fmaxf(b1x1, b2x1), 0.0f);
            const float ih = fmaxf(fminf(b1y2, b2y2) - fmaxf(b1y1, b2y1), 0.0f);
            const float inter = iw * ih;
            const float uni = w1 * h1 + w2 * h2 - inter + EPS;
            const float iou = inter / uni;

            const float cw = fmaxf(b1x2, b2x2) - fminf(b1x1, b2x1);
            const float ch = fmaxf(b1y2, b2y2) - fminf(b1y1, b2y1);
            const float c2 = cw * cw + ch * ch + EPS;
            const float dx = b2x1 + b2x2 - b1x1 - b1x2;
            const float dy = b2y1 + b2y2 - b1y1 - b1y2;
            const float rho2 = (dx * dx + dy * dy) * 0.25f;
            const float datan = atanf(w2 / (h2 + EPS)) - atanf(w1 / (h1 + EPS));
            const float v = (4.0f / (float)(M_PI * M_PI)) * datan * datan;
            const float alpha = v / (v - iou + 1.0f + EPS);
            const float ciou = 1.0f - iou + rho2 / c2 + alpha * v;
            box_v = fmaxf(ciou, 0.0f);

            const float area_p = fmaxf(p_w * p_h, EPS);
            const float area_t = fmaxf(t_w * t_h, EPS);
            float iou2 = inter / (area_p + area_t - inter + EPS);
            iou2 = fminf(fmaxf(iou2, 0.0f), 1.0f);
            corr_v = l0 * iou2;               // BCE correction term: -sum(l0*obj_t)
        }

        for (int off = 32; off > 0; off >>= 1) {
            box_v  += __shfl_down(box_v, off);
            corr_v += __shfl_down(corr_v, off);
            np_v   += __shfl_down(np_v, off);
        }
        const int wave = tid >> 6;
        if ((tid & 63) == 0) {
            s_redf[wave * 2 + 0] = box_v;
            s_redf[wave * 2 + 1] = corr_v;
            s_redi[wave] = np_v;
        }
        __syncthreads();
        if (tid == 0) {
            float box_t = 0.0f, corr_t = 0.0f; int np_t = 0;
            for (int w = 0; w < 4; w++) {
                box_t  += s_redf[w * 2 + 0];
                corr_t += s_redf[w * 2 + 1];
                np_t   += s_redi[w];
            }
            atomicAdd(&ws_f[0], -corr_t);                       // fold correction into bce sum
            atomicAdd(&ws_f[1], box_t / (float)max(np_t, 1));
            atomicAdd(&ws_i[0], np_t);
            if (np_t > 0) atomicAdd(&ws_i[1], 1);
        }
    }

    // ---------------- last-block finalize (atomics only, NO fences) ----------------
    if (tid == 0) {
        // ensure this block's accumulator atomics have reached the coherent point
        asm volatile("s_waitcnt vmcnt(0)" ::: "memory");
        const unsigned t = atomicAdd(ws_counter, 1u);
        if (t == (unsigned)(gridDim.x - 1)) {
            // coherent reads via identity atomics
            const float bce_corr = atomicAdd(&ws_f[0], 0.0f);
            const float box      = atomicAdd(&ws_f[1], 0.0f);
            const int   pos      = atomicAdd(&ws_i[0], 0);
            const int   items    = atomicAdd(&ws_i[1], 0);
            const float total_obj = bce_corr / fmaxf((float)pos, 1.0f);
            const float total_box = box / (float)max(items, 1);
            out[0] = total_obj + 5.0f * total_box;
        }
    }
}

extern "C" void kernel_launch(void* const* d_in, const int* in_sizes, int n_in,
                              void* d_out, int out_size, void* d_ws, size_t ws_size,
                              hipStream_t stream)
{
    const float* pred0 = (const float*)d_in[0];
    const float* pred1 = (const float*)d_in[1];
    const float* pred2 = (const float*)d_in[2];
    const float* gt    = (const float*)d_in[3];
    float* out = (float*)d_out;

    const int B   = in_sizes[3] / (32 * 4);   // 512
    const int nPL = 3 * B;                    // 1536

    // ws layout: counter(4B) pad(12B) | ws_f[2] | ws_i[2]
    unsigned* ws_counter = (unsigned*)d_ws;
    float* ws_f = (float*)((char*)d_ws + 16);
    int*   ws_i = (int*)((char*)d_ws + 24);

    hipMemsetAsync(d_ws, 0, 32, stream);
    det_main<<<dim3(NB_BCE + nPL), dim3(256), 0, stream>>>(
        pred0, pred1, pred2, gt, ws_counter, ws_f, ws_i, B, out);
}

// Round 5
// 16.654 us; speedup vs baseline: 12.0337x; 7.7769x over previous
//
#include <hip/hip_runtime.h>
#include <math.h>

#define EPS 1e-7f
#define NB_BCE 1024   // blocks doing the BCE base-sum role
#define NB_IMG 512    // one positives block per image (3 levels inside)

// BCE-with-logits base term (target-independent part): max(l,0) + log1p(exp(-|l|))
__device__ __forceinline__ float bce_base(float l) {
    return fmaxf(l, 0.0f) + __logf(1.0f + __expf(-fabsf(l)));
}

__device__ __forceinline__ float sigmoidf_(float x) { return 1.0f / (1.0f + expf(-x)); }

// Kernel 1. blocks [0, NB_BCE): grid-stride BCE base sum over channel 0 of all
// levels -> ws_c[bid]. blocks [NB_BCE, NB_BCE+B): per-image positives work, all
// 3 levels sequentially in one block -> ws_box/ws_corr/ws_npos/ws_items[b].
// No global atomics, no fences. Plain stores to distinct slots only.
__global__ __launch_bounds__(256) void det_main(
    const float* __restrict__ pred0,   // (B,5,52,52)
    const float* __restrict__ pred1,   // (B,5,26,26)
    const float* __restrict__ pred2,   // (B,5,13,13)
    const float* __restrict__ gt,      // (B,32,4)
    float*       ws_c,                 // [NB_BCE]
    float*       ws_box,               // [B]   sum over levels of box_sum/max(npos,1)
    float*       ws_corr,              // [B]   sum over levels of sum(l0*obj_t)
    int*         ws_npos,              // [B]   sum over levels of npos
    int*         ws_items,             // [B]   count of levels with npos>0
    int B)
{
    __shared__ int   s_map[52 * 52];
    __shared__ float s_gt[128];
    __shared__ int   s_cell[96];
    __shared__ float s_redf[8];
    __shared__ int   s_redi[4];

    const int tid = threadIdx.x;
    const int bid = blockIdx.x;

    if (bid < NB_BCE) {
        // ---------------- BCE base role ----------------
        const unsigned E0 = (unsigned)B * 2704u;
        const unsigned E1 = (unsigned)B * 676u;
        const unsigned E2 = (unsigned)B * 169u;
        const unsigned NV4 = (E0 + E1) >> 2;               // float4 items (both %4==0)
        float acc = 0.0f;

        for (unsigned v = (unsigned)bid * 256u + tid; v < NV4; v += NB_BCE * 256u) {
            const unsigned idx = v << 2;
            const float* p;
            if (idx < E0) {
                const unsigned b = idx / 2704u;
                const unsigned i = idx - b * 2704u;
                p = pred0 + (size_t)b * 13520u + i;
            } else {
                const unsigned j = idx - E0;
                const unsigned b = j / 676u;
                const unsigned i = j - b * 676u;
                p = pred1 + (size_t)b * 3380u + i;
            }
            const float4 l = *reinterpret_cast<const float4*>(p);
            acc += bce_base(l.x) + bce_base(l.y) + bce_base(l.z) + bce_base(l.w);
        }
        for (unsigned j = (unsigned)bid * 256u + tid; j < E2; j += NB_BCE * 256u) {
            const unsigned b = j / 169u;
            const unsigned i = j - b * 169u;
            acc += bce_base(pred2[(size_t)b * 845u + i]);
        }

        for (int off = 32; off > 0; off >>= 1) acc += __shfl_down(acc, off);
        if ((tid & 63) == 0) s_redf[tid >> 6] = acc;
        __syncthreads();
        if (tid == 0) ws_c[bid] = s_redf[0] + s_redf[1] + s_redf[2] + s_redf[3];
        return;
    }

    // ---------------- per-image positives role (3 levels sequentially) ----------------
    const int b = bid - NB_BCE;            // 0 .. B-1

    if (tid < 128) s_gt[tid] = gt[(size_t)b * 128 + tid];

    float box_acc = 0.0f, corr_acc = 0.0f; // live in tid 0 only
    int   np_acc = 0, it_acc = 0;

    for (int level = 0; level < 3; level++) {
        const float* pred;
        int Wd;
        if (level == 0)      { pred = pred0; Wd = 52; }
        else if (level == 1) { pred = pred1; Wd = 26; }
        else                 { pred = pred2; Wd = 13; }
        const int   HW = Wd * Wd;
        const float S  = (float)Wd;
        const float sc = 1.0f / S;

        __syncthreads();                   // s_gt ready (iter 0) / prev level done

        // candidate generation: 32 gts -> up to 96 (cell, gi); slot k has gi = k & 31
        if (tid < 32) {
            const int n = tid;
            const float gx = s_gt[n * 4 + 0] * S;
            const float gy = s_gt[n * 4 + 1] * S;
            int col = (int)gx; col = min(max(col, 0), Wd - 1);
            int row = (int)gy; row = min(max(row, 0), Wd - 1);
            const float off_x = gx - (float)col;
            const float off_y = gy - (float)row;
            s_cell[n] = row * Wd + col;
            int col_n, row_n; bool vx, vy;
            if (off_x < 0.5f) { col_n = col - 1; vx = (col > 0); }
            else              { col_n = col + 1; vx = (col < Wd - 1); }
            if (off_y < 0.5f) { row_n = row - 1; vy = (row > 0); }
            else              { row_n = row + 1; vy = (row < Wd - 1); }
            s_cell[32 + n] = vx ? (row * Wd + col_n) : -1;
            s_cell[64 + n] = vy ? (row_n * Wd + col) : -1;
        }
        __syncthreads();

        int c = -1;
        if (tid < 96) c = s_cell[tid];
        if (c >= 0) s_map[c] = -1;         // init only touched cells
        __syncthreads();
        if (c >= 0) atomicMax(&s_map[c], tid & 31);
        __syncthreads();

        const bool winner = (c >= 0) && (s_map[c] == (tid & 31));

        float box_v = 0.0f, corr_v = 0.0f;
        int np_v = 0;
        if (winner) {
            np_v = 1;
            const int gi = s_map[c];
            const float* base = pred + (size_t)b * 5 * HW;
            const float l0 = base[c];
            const float l1 = base[HW + c];
            const float l2 = base[2 * HW + c];
            const float l3 = base[3 * HW + c];
            const float l4 = base[4 * HW + c];
            const float ccol = (float)(c % Wd);
            const float crow = (float)(c / Wd);
            const float p_cx = (sigmoidf_(l1) * 2.0f - 0.5f + ccol) * sc;
            const float p_cy = (sigmoidf_(l2) * 2.0f - 0.5f + crow) * sc;
            const float p_w  = expf(fminf(fmaxf(l3, -5.0f), 5.0f)) * sc;
            const float p_h  = expf(fminf(fmaxf(l4, -5.0f), 5.0f)) * sc;
            const float t_cx = s_gt[gi * 4 + 0];
            const float t_cy = s_gt[gi * 4 + 1];
            const float t_w  = s_gt[gi * 4 + 2];
            const float t_h  = s_gt[gi * 4 + 3];

            const float b1x1 = p_cx - p_w * 0.5f, b1y1 = p_cy - p_h * 0.5f;
            const float b1x2 = p_cx + p_w * 0.5f, b1y2 = p_cy + p_h * 0.5f;
            const float b2x1 = t_cx - t_w * 0.5f, b2y1 = t_cy - t_h * 0.5f;
            const float b2x2 = t_cx + t_w * 0.5f, b2y2 = t_cy + t_h * 0.5f;

            const float w1 = b1x2 - b1x1, h1 = b1y2 - b1y1;
            const float w2 = b2x2 - b2x1, h2 = b2y2 - b2y1;

            const float iw = fmaxf(fminf(b1x2, b2x2) - fmaxf(b1x1, b2x1), 0.0f);
            const float ih = fmaxf(fminf(b1y2, b2y2) - fmaxf(b1y1, b2y1), 0.0f);
            const float inter = iw * ih;
            const float uni = w1 * h1 + w2 * h2 - inter + EPS;
            const float iou = inter / uni;

            const float cw = fmaxf(b1x2, b2x2) - fminf(b1x1, b2x1);
            const float ch = fmaxf(b1y2, b2y2) - fminf(b1y1, b2y1);
            const float c2 = cw * cw + ch * ch + EPS;
            const float dx = b2x1 + b2x2 - b1x1 - b1x2;
            const float dy = b2y1 + b2y2 - b1y1 - b1y2;
            const float rho2 = (dx * dx + dy * dy) * 0.25f;
            const float datan = atanf(w2 / (h2 + EPS)) - atanf(w1 / (h1 + EPS));
            const float v = (4.0f / (float)(M_PI * M_PI)) * datan * datan;
            const float alpha = v / (v - iou + 1.0f + EPS);
            const float ciou = 1.0f - iou + rho2 / c2 + alpha * v;
            box_v = fmaxf(ciou, 0.0f);

            const float area_p = fmaxf(p_w * p_h, EPS);
            const float area_t = fmaxf(t_w * t_h, EPS);
            float iou2 = inter / (area_p + area_t - inter + EPS);
            iou2 = fminf(fmaxf(iou2, 0.0f), 1.0f);
            corr_v = l0 * iou2;             // BCE correction term: -sum(l0*obj_t)
        }

        for (int off = 32; off > 0; off >>= 1) {
            box_v  += __shfl_down(box_v, off);
            corr_v += __shfl_down(corr_v, off);
            np_v   += __shfl_down(np_v, off);
        }
        const int wave = tid >> 6;
        if ((tid & 63) == 0) {
            s_redf[wave * 2 + 0] = box_v;
            s_redf[wave * 2 + 1] = corr_v;
            s_redi[wave] = np_v;
        }
        __syncthreads();
        if (tid == 0) {
            float box_t = 0.0f, corr_t = 0.0f; int np_t = 0;
            for (int w = 0; w < 4; w++) {
                box_t  += s_redf[w * 2 + 0];
                corr_t += s_redf[w * 2 + 1];
                np_t   += s_redi[w];
            }
            box_acc  += box_t / (float)max(np_t, 1);
            corr_acc += corr_t;
            np_acc   += np_t;
            it_acc   += (np_t > 0) ? 1 : 0;
        }
        // s_redf reuse is safe: next write is 3 syncs away
    }

    if (tid == 0) {
        ws_box[b]   = box_acc;
        ws_corr[b]  = corr_acc;
        ws_npos[b]  = np_acc;
        ws_items[b] = it_acc;
    }
}

__global__ __launch_bounds__(256) void det_final(
    const float* __restrict__ ws_c,
    const float* __restrict__ ws_box,
    const float* __restrict__ ws_corr,
    const int*   __restrict__ ws_npos,
    const int*   __restrict__ ws_items,
    int B,
    float* __restrict__ out)
{
    __shared__ float s_f[12];
    __shared__ int   s_i[8];
    const int tid = threadIdx.x;
    float box = 0.0f, corr = 0.0f, bce = 0.0f;
    int pos = 0, items = 0;
    for (int i = tid; i < B; i += 256) {
        box   += ws_box[i];
        corr  += ws_corr[i];
        pos   += ws_npos[i];
        items += ws_items[i];
    }
    for (int i = tid; i < NB_BCE; i += 256) bce += ws_c[i];

    for (int off = 32; off > 0; off >>= 1) {
        box   += __shfl_down(box, off);
        corr  += __shfl_down(corr, off);
        bce   += __shfl_down(bce, off);
        pos   += __shfl_down(pos, off);
        items += __shfl_down(items, off);
    }
    const int wave = tid >> 6;
    if ((tid & 63) == 0) {
        s_f[wave * 3 + 0] = box;
        s_f[wave * 3 + 1] = corr;
        s_f[wave * 3 + 2] = bce;
        s_i[wave * 2 + 0] = pos;
        s_i[wave * 2 + 1] = items;
    }
    __syncthreads();
    if (tid == 0) {
        float box_t = 0.0f, corr_t = 0.0f, bce_t = 0.0f;
        int pos_t = 0, it_t = 0;
        for (int w = 0; w < 4; w++) {
            box_t  += s_f[w * 3 + 0];
            corr_t += s_f[w * 3 + 1];
            bce_t  += s_f[w * 3 + 2];
            pos_t  += s_i[w * 2 + 0];
            it_t   += s_i[w * 2 + 1];
        }
        const float total_obj = (bce_t - corr_t) / fmaxf((float)pos_t, 1.0f);
        const float total_box = box_t / (float)max(it_t, 1);
        out[0] = total_obj + 5.0f * total_box;
    }
}

extern "C" void kernel_launch(void* const* d_in, const int* in_sizes, int n_in,
                              void* d_out, int out_size, void* d_ws, size_t ws_size,
                              hipStream_t stream)
{
    const float* pred0 = (const float*)d_in[0];
    const float* pred1 = (const float*)d_in[1];
    const float* pred2 = (const float*)d_in[2];
    const float* gt    = (const float*)d_in[3];
    float* out = (float*)d_out;

    const int B = in_sizes[3] / (32 * 4);   // 512

    // ws layout (floats): ws_c[NB_BCE] | ws_box[B] | ws_corr[B] | ws_npos[B] | ws_items[B]
    float* ws_c     = (float*)d_ws;
    float* ws_box   = ws_c + NB_BCE;
    float* ws_corr  = ws_box + B;
    int*   ws_npos  = (int*)(ws_corr + B);
    int*   ws_items = ws_npos + B;

    det_main<<<dim3(NB_BCE + B), dim3(256), 0, stream>>>(
        pred0, pred1, pred2, gt, ws_c, ws_box, ws_corr, ws_npos, ws_items, B);
    det_final<<<dim3(1), dim3(256), 0, stream>>>(
        ws_c, ws_box, ws_corr, ws_npos, ws_items, B, out);
}

// Round 6
// 15.987 us; speedup vs baseline: 12.5356x; 1.0417x over previous
//
#include <hip/hip_runtime.h>
#include <math.h>

#define EPS 1e-7f
#define NB_BCE 1024   // blocks doing the BCE base-sum role

// BCE-with-logits base term (target-independent part): max(l,0) + log1p(exp(-|l|))
__device__ __forceinline__ float bce_base(float l) {
    return fmaxf(l, 0.0f) + __logf(1.0f + __expf(-fabsf(l)));
}

__device__ __forceinline__ float sigmoidf_(float x) { return 1.0f / (1.0f + expf(-x)); }

// Kernel 1.
//  blocks [0, NB_BCE)           : grid-stride BCE base sum over channel 0 -> ws_c[bid]
//  blocks [NB_BCE, NB_BCE+3B)   : per-(image,level) positives work, SINGLE WAVE,
//                                 no __syncthreads -> ws_pl[pbid] = {box/max(np,1), corr, np, np>0}
// No global atomics, no device fences. Plain stores to distinct slots only;
// visibility to kernel 2 is provided by the inter-dispatch flush (proven r2/r5).
__global__ __launch_bounds__(256) void det_main(
    const float* __restrict__ pred0,   // (B,5,52,52)
    const float* __restrict__ pred1,   // (B,5,26,26)
    const float* __restrict__ pred2,   // (B,5,13,13)
    const float* __restrict__ gt,      // (B,32,4)
    float*       ws_c,                 // [NB_BCE]
    float4*      ws_pl,                // [3B]
    int B)
{
    __shared__ int   s_map[52 * 52];
    __shared__ float s_redf[4];

    const int tid = threadIdx.x;
    const int bid = blockIdx.x;

    if (bid < NB_BCE) {
        // ---------------- BCE base role ----------------
        const unsigned E0 = (unsigned)B * 2704u;
        const unsigned E1 = (unsigned)B * 676u;
        const unsigned E2 = (unsigned)B * 169u;
        const unsigned NV4 = (E0 + E1) >> 2;               // float4 items (both %4==0)
        float acc = 0.0f;

        for (unsigned v = (unsigned)bid * 256u + tid; v < NV4; v += NB_BCE * 256u) {
            const unsigned idx = v << 2;
            const float* p;
            if (idx < E0) {
                const unsigned b = idx / 2704u;
                const unsigned i = idx - b * 2704u;
                p = pred0 + (size_t)b * 13520u + i;
            } else {
                const unsigned j = idx - E0;
                const unsigned b = j / 676u;
                const unsigned i = j - b * 676u;
                p = pred1 + (size_t)b * 3380u + i;
            }
            const float4 l = *reinterpret_cast<const float4*>(p);
            acc += bce_base(l.x) + bce_base(l.y) + bce_base(l.z) + bce_base(l.w);
        }
        for (unsigned j = (unsigned)bid * 256u + tid; j < E2; j += NB_BCE * 256u) {
            const unsigned b = j / 169u;
            const unsigned i = j - b * 169u;
            acc += bce_base(pred2[(size_t)b * 845u + i]);
        }

        for (int off = 32; off > 0; off >>= 1) acc += __shfl_down(acc, off);
        if ((tid & 63) == 0) s_redf[tid >> 6] = acc;
        __syncthreads();
        if (tid == 0) ws_c[bid] = s_redf[0] + s_redf[1] + s_redf[2] + s_redf[3];
        return;
    }

    // ---------------- positives role: one wave, no barriers ----------------
    if (tid >= 64) return;                 // waves 1-3 exit; no __syncthreads below

    const int pbid  = bid - NB_BCE;        // 0 .. 3B-1
    const int level = pbid % 3;
    const int b     = pbid / 3;

    const float* pred;
    int Wd;
    if (level == 0)      { pred = pred0; Wd = 52; }
    else if (level == 1) { pred = pred1; Wd = 26; }
    else                 { pred = pred2; Wd = 13; }
    const int   HW = Wd * Wd;
    const float S  = (float)Wd;
    const float sc = 1.0f / S;

    float box_v = 0.0f, corr_v = 0.0f, np_v = 0.0f;

    if (tid < 32) {
        const int n = tid;
        const float4 g = *reinterpret_cast<const float4*>(gt + (size_t)b * 128 + n * 4);

        const float gx = g.x * S;
        const float gy = g.y * S;
        int col = (int)gx; col = min(max(col, 0), Wd - 1);
        int row = (int)gy; row = min(max(row, 0), Wd - 1);
        const float off_x = gx - (float)col;
        const float off_y = gy - (float)row;

        int col_n, row_n; bool vx, vy;
        if (off_x < 0.5f) { col_n = col - 1; vx = (col > 0); }
        else              { col_n = col + 1; vx = (col < Wd - 1); }
        if (off_y < 0.5f) { row_n = row - 1; vy = (row > 0); }
        else              { row_n = row + 1; vy = (row < Wd - 1); }

        int cs[3];
        cs[0] = row * Wd + col;
        cs[1] = vx ? (row * Wd + col_n) : -1;
        cs[2] = vy ? (row_n * Wd + col) : -1;

        // init touched cells, scatter-max gi, read winners — single wave, LDS-only fences
        s_map[cs[0]] = -1;
        if (cs[1] >= 0) s_map[cs[1]] = -1;
        if (cs[2] >= 0) s_map[cs[2]] = -1;
        __threadfence_block();
        atomicMax(&s_map[cs[0]], n);
        if (cs[1] >= 0) atomicMax(&s_map[cs[1]], n);
        if (cs[2] >= 0) atomicMax(&s_map[cs[2]], n);
        __threadfence_block();

        const float* base = pred + (size_t)b * 5 * HW;

        // winner s_map[c]==n  =>  winning gt row is THIS lane's g (in registers)
        const float t_cx = g.x, t_cy = g.y, t_w = g.z, t_h = g.w;
        const float b2x1 = t_cx - t_w * 0.5f, b2y1 = t_cy - t_h * 0.5f;
        const float b2x2 = t_cx + t_w * 0.5f, b2y2 = t_cy + t_h * 0.5f;
        const float w2 = b2x2 - b2x1, h2 = b2y2 - b2y1;
        const float atan2_ = atanf(w2 / (h2 + EPS));
        const float area_t = fmaxf(t_w * t_h, EPS);

        #pragma unroll
        for (int k = 0; k < 3; k++) {
            const int c = cs[k];
            if (c >= 0 && s_map[c] == n) {
                np_v += 1.0f;
                const float l0 = base[c];
                const float l1 = base[HW + c];
                const float l2 = base[2 * HW + c];
                const float l3 = base[3 * HW + c];
                const float l4 = base[4 * HW + c];
                const float ccol = (float)(c % Wd);
                const float crow = (float)(c / Wd);
                const float p_cx = (sigmoidf_(l1) * 2.0f - 0.5f + ccol) * sc;
                const float p_cy = (sigmoidf_(l2) * 2.0f - 0.5f + crow) * sc;
                const float p_w  = expf(fminf(fmaxf(l3, -5.0f), 5.0f)) * sc;
                const float p_h  = expf(fminf(fmaxf(l4, -5.0f), 5.0f)) * sc;

                const float b1x1 = p_cx - p_w * 0.5f, b1y1 = p_cy - p_h * 0.5f;
                const float b1x2 = p_cx + p_w * 0.5f, b1y2 = p_cy + p_h * 0.5f;
                const float w1 = b1x2 - b1x1, h1 = b1y2 - b1y1;

                const float iw = fmaxf(fminf(b1x2, b2x2) - fmaxf(b1x1, b2x1), 0.0f);
                const float ih = fmaxf(fminf(b1y2, b2y2) - fmaxf(b1y1, b2y1), 0.0f);
                const float inter = iw * ih;
                const float uni = w1 * h1 + w2 * h2 - inter + EPS;
                const float iou = inter / uni;

                const float cw = fmaxf(b1x2, b2x2) - fminf(b1x1, b2x1);
                const float ch = fmaxf(b1y2, b2y2) - fminf(b1y1, b2y1);
                const float c2 = cw * cw + ch * ch + EPS;
                const float dx = b2x1 + b2x2 - b1x1 - b1x2;
                const float dy = b2y1 + b2y2 - b1y1 - b1y2;
                const float rho2 = (dx * dx + dy * dy) * 0.25f;
                const float datan = atan2_ - atanf(w1 / (h1 + EPS));
                const float v = (4.0f / (float)(M_PI * M_PI)) * datan * datan;
                const float alpha = v / (v - iou + 1.0f + EPS);
                const float ciou = 1.0f - iou + rho2 / c2 + alpha * v;
                box_v += fmaxf(ciou, 0.0f);

                const float area_p = fmaxf(p_w * p_h, EPS);
                float iou2 = inter / (area_p + area_t - inter + EPS);
                iou2 = fminf(fmaxf(iou2, 0.0f), 1.0f);
                corr_v += l0 * iou2;          // BCE correction: -sum(l0*obj_t)
            }
        }
    }

    // 64-lane wave reduce (lanes 32-63 hold zeros)
    for (int off = 32; off > 0; off >>= 1) {
        box_v  += __shfl_down(box_v, off);
        corr_v += __shfl_down(corr_v, off);
        np_v   += __shfl_down(np_v, off);
    }
    if (tid == 0) {
        const float np = np_v;
        ws_pl[pbid] = make_float4(box_v / fmaxf(np, 1.0f), corr_v, np, (np > 0.0f) ? 1.0f : 0.0f);
    }
}

__global__ __launch_bounds__(256) void det_final(
    const float*  __restrict__ ws_c,
    const float4* __restrict__ ws_pl,
    int nPL,                              // 3B
    float* __restrict__ out)
{
    __shared__ float s_f[20];
    const int tid = threadIdx.x;
    float box = 0.0f, corr = 0.0f, bce = 0.0f, pos = 0.0f, items = 0.0f;
    for (int i = tid; i < nPL; i += 256) {
        const float4 v = ws_pl[i];
        box += v.x; corr += v.y; pos += v.z; items += v.w;
    }
    for (int i = tid; i < NB_BCE; i += 256) bce += ws_c[i];

    for (int off = 32; off > 0; off >>= 1) {
        box   += __shfl_down(box, off);
        corr  += __shfl_down(corr, off);
        bce   += __shfl_down(bce, off);
        pos   += __shfl_down(pos, off);
        items += __shfl_down(items, off);
    }
    const int wave = tid >> 6;
    if ((tid & 63) == 0) {
        s_f[wave * 5 + 0] = box;
        s_f[wave * 5 + 1] = corr;
        s_f[wave * 5 + 2] = bce;
        s_f[wave * 5 + 3] = pos;
        s_f[wave * 5 + 4] = items;
    }
    __syncthreads();
    if (tid == 0) {
        float box_t = 0.0f, corr_t = 0.0f, bce_t = 0.0f, pos_t = 0.0f, it_t = 0.0f;
        for (int w = 0; w < 4; w++) {
            box_t  += s_f[w * 5 + 0];
            corr_t += s_f[w * 5 + 1];
            bce_t  += s_f[w * 5 + 2];
            pos_t  += s_f[w * 5 + 3];
            it_t   += s_f[w * 5 + 4];
        }
        const float total_obj = (bce_t - corr_t) / fmaxf(pos_t, 1.0f);
        const float total_box = box_t / fmaxf(it_t, 1.0f);
        out[0] = total_obj + 5.0f * total_box;
    }
}

extern "C" void kernel_launch(void* const* d_in, const int* in_sizes, int n_in,
                              void* d_out, int out_size, void* d_ws, size_t ws_size,
                              hipStream_t stream)
{
    const float* pred0 = (const float*)d_in[0];
    const float* pred1 = (const float*)d_in[1];
    const float* pred2 = (const float*)d_in[2];
    const float* gt    = (const float*)d_in[3];
    float* out = (float*)d_out;

    const int B   = in_sizes[3] / (32 * 4);   // 512
    const int nPL = 3 * B;                    // 1536

    // ws layout: ws_c[NB_BCE] floats | ws_pl[nPL] float4 (offset 4096 B, 16-aligned)
    float*  ws_c  = (float*)d_ws;
    float4* ws_pl = (float4*)((char*)d_ws + NB_BCE * sizeof(float));

    det_main<<<dim3(NB_BCE + nPL), dim3(256), 0, stream>>>(
        pred0, pred1, pred2, gt, ws_c, ws_pl, B);
    det_final<<<dim3(1), dim3(256), 0, stream>>>(ws_c, ws_pl, nPL, out);
}

// Round 7
// 14.953 us; speedup vs baseline: 13.4031x; 1.0692x over previous
//
#include <hip/hip_runtime.h>
#include <math.h>

#define EPS 1e-7f
#define NB_BCE 512    // blocks doing the BCE base-sum role (grid total = 3B + 512 = 2048)

// BCE-with-logits base term (target-independent part): max(l,0) + log1p(exp(-|l|))
__device__ __forceinline__ float bce_base(float l) {
    return fmaxf(l, 0.0f) + __logf(1.0f + __expf(-fabsf(l)));
}

__device__ __forceinline__ float sigmoidf_(float x) { return 1.0f / (1.0f + expf(-x)); }

// Kernel 1. Grid = 3B + NB_BCE = 2048 blocks = exactly one scheduling round
// (8 blocks/CU x 256 CU at the 2048-thread cap).
//  blocks [0, 3B)           : per-(image,level) positives work, SINGLE WAVE, no barriers
//                             -> ws_pl[bid] = {box/max(np,1), corr, np, np>0}
//  blocks [3B, 3B+NB_BCE)   : grid-stride BCE base sum over channel 0 -> ws_c[...]
// Positives blocks dispatched FIRST so the short latency-bound blocks overlap the
// streaming BCE blocks instead of trailing them.
// No global atomics, no device fences; plain stores to distinct slots only
// (inter-dispatch flush provides visibility to kernel 2 — proven r2/r5/r6).
__global__ __launch_bounds__(256) void det_main(
    const float* __restrict__ pred0,   // (B,5,52,52)
    const float* __restrict__ pred1,   // (B,5,26,26)
    const float* __restrict__ pred2,   // (B,5,13,13)
    const float* __restrict__ gt,      // (B,32,4)
    float*       ws_c,                 // [NB_BCE]
    float4*      ws_pl,                // [3B]
    int B)
{
    __shared__ int   s_map[52 * 52];
    __shared__ float s_redf[4];

    const int tid = threadIdx.x;
    const int bid = blockIdx.x;
    const int nPL = 3 * B;

    if (bid >= nPL) {
        // ---------------- BCE base role ----------------
        const int cbid = bid - nPL;                        // 0 .. NB_BCE-1
        const unsigned E0 = (unsigned)B * 2704u;
        const unsigned E1 = (unsigned)B * 676u;
        const unsigned E2 = (unsigned)B * 169u;
        const unsigned NV4 = (E0 + E1) >> 2;               // float4 items (both %4==0)
        float acc = 0.0f;

        for (unsigned v = (unsigned)cbid * 256u + tid; v < NV4; v += NB_BCE * 256u) {
            const unsigned idx = v << 2;
            const float* p;
            if (idx < E0) {
                const unsigned b = idx / 2704u;
                const unsigned i = idx - b * 2704u;
                p = pred0 + (size_t)b * 13520u + i;
            } else {
                const unsigned j = idx - E0;
                const unsigned b = j / 676u;
                const unsigned i = j - b * 676u;
                p = pred1 + (size_t)b * 3380u + i;
            }
            const float4 l = *reinterpret_cast<const float4*>(p);
            acc += bce_base(l.x) + bce_base(l.y) + bce_base(l.z) + bce_base(l.w);
        }
        for (unsigned j = (unsigned)cbid * 256u + tid; j < E2; j += NB_BCE * 256u) {
            const unsigned b = j / 169u;
            const unsigned i = j - b * 169u;
            acc += bce_base(pred2[(size_t)b * 845u + i]);
        }

        for (int off = 32; off > 0; off >>= 1) acc += __shfl_down(acc, off);
        if ((tid & 63) == 0) s_redf[tid >> 6] = acc;
        __syncthreads();
        if (tid == 0) ws_c[cbid] = s_redf[0] + s_redf[1] + s_redf[2] + s_redf[3];
        return;
    }

    // ---------------- positives role: one wave, no barriers ----------------
    if (tid >= 64) return;                 // waves 1-3 exit; no __syncthreads below

    const int pbid  = bid;                 // 0 .. 3B-1
    const int level = pbid % 3;
    const int b     = pbid / 3;

    const float* pred;
    int Wd;
    if (level == 0)      { pred = pred0; Wd = 52; }
    else if (level == 1) { pred = pred1; Wd = 26; }
    else                 { pred = pred2; Wd = 13; }
    const int   HW = Wd * Wd;
    const float S  = (float)Wd;
    const float sc = 1.0f / S;

    float box_v = 0.0f, corr_v = 0.0f, np_v = 0.0f;

    if (tid < 32) {
        const int n = tid;
        const float4 g = *reinterpret_cast<const float4*>(gt + (size_t)b * 128 + n * 4);

        const float gx = g.x * S;
        const float gy = g.y * S;
        int col = (int)gx; col = min(max(col, 0), Wd - 1);
        int row = (int)gy; row = min(max(row, 0), Wd - 1);
        const float off_x = gx - (float)col;
        const float off_y = gy - (float)row;

        int col_n, row_n; bool vx, vy;
        if (off_x < 0.5f) { col_n = col - 1; vx = (col > 0); }
        else              { col_n = col + 1; vx = (col < Wd - 1); }
        if (off_y < 0.5f) { row_n = row - 1; vy = (row > 0); }
        else              { row_n = row + 1; vy = (row < Wd - 1); }

        int cs[3];
        cs[0] = row * Wd + col;
        cs[1] = vx ? (row * Wd + col_n) : -1;
        cs[2] = vy ? (row_n * Wd + col) : -1;

        // init touched cells, scatter-max gi, read winners — single wave, LDS-only fences
        s_map[cs[0]] = -1;
        if (cs[1] >= 0) s_map[cs[1]] = -1;
        if (cs[2] >= 0) s_map[cs[2]] = -1;
        __threadfence_block();
        atomicMax(&s_map[cs[0]], n);
        if (cs[1] >= 0) atomicMax(&s_map[cs[1]], n);
        if (cs[2] >= 0) atomicMax(&s_map[cs[2]], n);
        __threadfence_block();

        const float* base = pred + (size_t)b * 5 * HW;

        // winner s_map[c]==n  =>  winning gt row is THIS lane's g (in registers)
        const float t_cx = g.x, t_cy = g.y, t_w = g.z, t_h = g.w;
        const float b2x1 = t_cx - t_w * 0.5f, b2y1 = t_cy - t_h * 0.5f;
        const float b2x2 = t_cx + t_w * 0.5f, b2y2 = t_cy + t_h * 0.5f;
        const float w2 = b2x2 - b2x1, h2 = b2y2 - b2y1;
        const float atan2_ = atanf(w2 / (h2 + EPS));
        const float area_t = fmaxf(t_w * t_h, EPS);

        #pragma unroll
        for (int k = 0; k < 3; k++) {
            const int c = cs[k];
            if (c >= 0 && s_map[c] == n) {
                np_v += 1.0f;
                const float l0 = base[c];
                const float l1 = base[HW + c];
                const float l2 = base[2 * HW + c];
                const float l3 = base[3 * HW + c];
                const float l4 = base[4 * HW + c];
                const float ccol = (float)(c % Wd);
                const float crow = (float)(c / Wd);
                const float p_cx = (sigmoidf_(l1) * 2.0f - 0.5f + ccol) * sc;
                const float p_cy = (sigmoidf_(l2) * 2.0f - 0.5f + crow) * sc;
                const float p_w  = expf(fminf(fmaxf(l3, -5.0f), 5.0f)) * sc;
                const float p_h  = expf(fminf(fmaxf(l4, -5.0f), 5.0f)) * sc;

                const float b1x1 = p_cx - p_w * 0.5f, b1y1 = p_cy - p_h * 0.5f;
                const float b1x2 = p_cx + p_w * 0.5f, b1y2 = p_cy + p_h * 0.5f;
                const float w1 = b1x2 - b1x1, h1 = b1y2 - b1y1;

                const float iw = fmaxf(fminf(b1x2, b2x2) - fmaxf(b1x1, b2x1), 0.0f);
                const float ih = fmaxf(fminf(b1y2, b2y2) - fmaxf(b1y1, b2y1), 0.0f);
                const float inter = iw * ih;
                const float uni = w1 * h1 + w2 * h2 - inter + EPS;
                const float iou = inter / uni;

                const float cw = fmaxf(b1x2, b2x2) - fminf(b1x1, b2x1);
                const float ch = fmaxf(b1y2, b2y2) - fminf(b1y1, b2y1);
                const float c2 = cw * cw + ch * ch + EPS;
                const float dx = b2x1 + b2x2 - b1x1 - b1x2;
                const float dy = b2y1 + b2y2 - b1y1 - b1y2;
                const float rho2 = (dx * dx + dy * dy) * 0.25f;
                const float datan = atan2_ - atanf(w1 / (h1 + EPS));
                const float v = (4.0f / (float)(M_PI * M_PI)) * datan * datan;
                const float alpha = v / (v - iou + 1.0f + EPS);
                const float ciou = 1.0f - iou + rho2 / c2 + alpha * v;
                box_v += fmaxf(ciou, 0.0f);

                const float area_p = fmaxf(p_w * p_h, EPS);
                float iou2 = inter / (area_p + area_t - inter + EPS);
                iou2 = fminf(fmaxf(iou2, 0.0f), 1.0f);
                corr_v += l0 * iou2;          // BCE correction: -sum(l0*obj_t)
            }
        }
    }

    // 64-lane wave reduce (lanes 32-63 hold zeros)
    for (int off = 32; off > 0; off >>= 1) {
        box_v  += __shfl_down(box_v, off);
        corr_v += __shfl_down(corr_v, off);
        np_v   += __shfl_down(np_v, off);
    }
    if (tid == 0) {
        const float np = np_v;
        ws_pl[pbid] = make_float4(box_v / fmaxf(np, 1.0f), corr_v, np, (np > 0.0f) ? 1.0f : 0.0f);
    }
}

__global__ __launch_bounds__(256) void det_final(
    const float*  __restrict__ ws_c,
    const float4* __restrict__ ws_pl,
    int nPL,                              // 3B
    float* __restrict__ out)
{
    __shared__ float s_f[20];
    const int tid = threadIdx.x;
    float box = 0.0f, corr = 0.0f, bce = 0.0f, pos = 0.0f, items = 0.0f;
    for (int i = tid; i < nPL; i += 256) {
        const float4 v = ws_pl[i];
        box += v.x; corr += v.y; pos += v.z; items += v.w;
    }
    for (int i = tid; i < NB_BCE; i += 256) bce += ws_c[i];

    for (int off = 32; off > 0; off >>= 1) {
        box   += __shfl_down(box, off);
        corr  += __shfl_down(corr, off);
        bce   += __shfl_down(bce, off);
        pos   += __shfl_down(pos, off);
        items += __shfl_down(items, off);
    }
    const int wave = tid >> 6;
    if ((tid & 63) == 0) {
        s_f[wave * 5 + 0] = box;
        s_f[wave * 5 + 1] = corr;
        s_f[wave * 5 + 2] = bce;
        s_f[wave * 5 + 3] = pos;
        s_f[wave * 5 + 4] = items;
    }
    __syncthreads();
    if (tid == 0) {
        float box_t = 0.0f, corr_t = 0.0f, bce_t = 0.0f, pos_t = 0.0f, it_t = 0.0f;
        for (int w = 0; w < 4; w++) {
            box_t  += s_f[w * 5 + 0];
            corr_t += s_f[w * 5 + 1];
            bce_t  += s_f[w * 5 + 2];
            pos_t  += s_f[w * 5 + 3];
            it_t   += s_f[w * 5 + 4];
        }
        const float total_obj = (bce_t - corr_t) / fmaxf(pos_t, 1.0f);
        const float total_box = box_t / fmaxf(it_t, 1.0f);
        out[0] = total_obj + 5.0f * total_box;
    }
}

extern "C" void kernel_launch(void* const* d_in, const int* in_sizes, int n_in,
                              void* d_out, int out_size, void* d_ws, size_t ws_size,
                              hipStream_t stream)
{
    const float* pred0 = (const float*)d_in[0];
    const float* pred1 = (const float*)d_in[1];
    const float* pred2 = (const float*)d_in[2];
    const float* gt    = (const float*)d_in[3];
    float* out = (float*)d_out;

    const int B   = in_sizes[3] / (32 * 4);   // 512
    const int nPL = 3 * B;                    // 1536

    // ws layout: ws_c[NB_BCE] floats | ws_pl[nPL] float4 (offset 2048 B, 16-aligned)
    float*  ws_c  = (float*)d_ws;
    float4* ws_pl = (float4*)((char*)d_ws + NB_BCE * sizeof(float));

    det_main<<<dim3(nPL + NB_BCE), dim3(256), 0, stream>>>(
        pred0, pred1, pred2, gt, ws_c, ws_pl, B);
    det_final<<<dim3(1), dim3(256), 0, stream>>>(ws_c, ws_pl, nPL, out);
}